// Round 8
// baseline (595.623 us; speedup 1.0000x reference)
//
#include <hip/hip_runtime.h>
#include <math.h>

#define B_ 16
#define CIN_ 3
#define HID_ 64
#define S_ 16384
#define MODES_ 16
#define HEADS_ 4
#define CH_ 16
#define ED_ 8
#define NPSP_ 500
#define NPFR_ 200
#define LAYERS_ 4
#define RECW_ 42                      // per-channel packed record, doubles

// gelu(v), erf via 12-term odd Taylor in y=v/sqrt(2); |err|<2e-14 for |v|<=1,
// rare libm fallback. h stored f32 (3e-9 rounding) dominates — poly is free.
__device__ __forceinline__ double gelu_exact(double v) {
    double y = v * 0.70710678118654752440;
    double t = y * y;
    double p = -1.2290555301717926e-09;
    p = fma(p, t, 1.4807192815879218e-08);
    p = fma(p, t, -1.6365838718281893e-07);
    p = fma(p, t, 1.6462114365889246e-06);
    p = fma(p, t, -1.4925650358406251e-05);
    p = fma(p, t, 1.2055332981789664e-04);
    p = fma(p, t, -8.5483270234508528e-04);
    p = fma(p, t, 5.2239776254421878e-03);
    p = fma(p, t, -2.6866170645131252e-02);
    p = fma(p, t, 1.1283791670955126e-01);
    p = fma(p, t, -3.7612638903183752e-01);
    p = fma(p, t, 1.1283791670955126e+00);
    double er = y * p;
    if (t > 0.5000001) er = erf(y);
    return 0.5 * v * (1.0 + er);
}

// cos(m*pi/32), sin(m*pi/32), m = 0..15
__device__ __constant__ double KC_[16] = {1.0, 0.99518472667219688624,
    0.98078528040323044913, 0.95694033573220886494, 0.92387953251128675613,
    0.88192126434835502971, 0.83146961230254523708, 0.77301045336273696081,
    0.70710678118654752440, 0.63439328416364549822, 0.55557023301960222474,
    0.47139673682599764856, 0.38268343236508977173, 0.29028467725446236764,
    0.19509032201612826785, 0.09801714032956060199};
__device__ __constant__ double KS_[16] = {0.0, 0.09801714032956060199,
    0.19509032201612826785, 0.29028467725446236764, 0.38268343236508977173,
    0.47139673682599764856, 0.55557023301960222474, 0.63439328416364549822,
    0.70710678118654752440, 0.77301045336273696081, 0.83146961230254523708,
    0.88192126434835502971, 0.92387953251128675613, 0.95694033573220886494,
    0.98078528040323044913, 0.99518472667219688624};

// ---------------------------------------------------------------------------
// Lift: h[b,d,s] = sum_c x[b,c,s]*W[c,d] + bias[d].  Channel-sum written as
// two partials (d<32 / d>=32) matching k_recon's split-channel layout.
// ---------------------------------------------------------------------------
__global__ __launch_bounds__(256) void k_lift(const float* __restrict__ x,
                                              const float* __restrict__ W,
                                              const float* __restrict__ bias,
                                              float* __restrict__ h,
                                              double* __restrict__ sC2) {
    int b = blockIdx.y;
    int s = blockIdx.x * 256 + threadIdx.x;
    const float* xb = x + (size_t)b * CIN_ * S_ + s;
    double x0 = (double)xb[0];
    double x1 = (double)xb[S_];
    double x2 = (double)xb[2 * S_];
    float* hb = h + (size_t)b * HID_ * S_ + s;
    double accA = 0.0, accB = 0.0;
    for (int d = 0; d < HID_; ++d) {
        double v = x0 * (double)W[d];
        v = fma(x1, (double)W[HID_ + d], v);
        v = fma(x2, (double)W[2 * HID_ + d], v);
        v += (double)bias[d];
        hb[(size_t)d * S_] = (float)v;
        if (d < 32) accA += v; else accB += v;
    }
    sC2[(size_t)b * S_ + s] = accA;
    sC2[(size_t)(B_ + b) * S_ + s] = accB;
}

// ---------------------------------------------------------------------------
// Spatial hash: wsum window over (sC2 half0 + half1), idx, block-reduced
// embedding sum (Eb).
// ---------------------------------------------------------------------------
__global__ __launch_bounds__(256) void k_hash(const double* __restrict__ sC2,
                                              const float* __restrict__ emb_l,
                                              int* __restrict__ idx,
                                              double* __restrict__ Eb) {
    int b = blockIdx.y;
    int s0 = blockIdx.x * 256;
    int t = threadIdx.x;
    __shared__ double sl[260];
    for (int j = t; j < 260; j += 256) {
        int p = s0 - 2 + j;
        p = p < 0 ? 0 : (p > S_ - 1 ? S_ - 1 : p);
        sl[j] = sC2[(size_t)b * S_ + p] + sC2[(size_t)(B_ + b) * S_ + p];
    }
    __syncthreads();
    double wsum = ((sl[t] + sl[t + 1]) + sl[t + 2]) + sl[t + 3];
    int ti = (int)(wsum * 31.0);
    int id = ti % NPSP_;
    if (id < 0) id += NPSP_;
    idx[(size_t)b * S_ + s0 + t] = id;

    const float* er = emb_l + id * ED_;
    double ev[8];
#pragma unroll
    for (int k = 0; k < 8; k++) ev[k] = (double)er[k];

    int lane = t & 63, wv = t >> 6;
    __shared__ double red[4][8];
#pragma unroll
    for (int k = 0; k < 8; k++) {
        double v = ev[k];
        for (int off = 32; off > 0; off >>= 1) v += __shfl_down(v, off, 64);
        if (lane == 0) red[wv][k] = v;
    }
    __syncthreads();
    if (t < 8) {
        double v = red[0][t] + red[1][t] + red[2][t] + red[3][t];
        atomicAdd(&Eb[b * ED_ + t], v);
    }
}

// ---------------------------------------------------------------------------
// 16-mode DFT, radix-4 decimation, 2 channels/block — ROUND-5 PROVEN SHAPE.
// __launch_bounds__(256, 2) is LOAD-BEARING: the 2-waves/EU budget lets the
// ~128-double accumulator/twiddle file live in the unified VGPR/AGPR file.
// Round-6's plain (256) variant spilled 660 MB/dispatch to scratch.
// ---------------------------------------------------------------------------
__global__ __launch_bounds__(256, 2) void k_dft(const float* __restrict__ h,
                                                double* __restrict__ Xr,
                                                double* __restrict__ Xi) {
    int b = blockIdx.y;
    int c0 = blockIdx.x * 2;
    int t = threadIdx.x;
    const float* h0 = h + ((size_t)(b * HID_ + c0)) * S_ + t;
    const float* h1 = h0 + S_;

    double acc[64];
#pragma unroll
    for (int k = 0; k < 64; k++) acc[k] = 0.0;

    double cmv[16], smv[16];
    cmv[0] = 1.0; smv[0] = 0.0;
    cmv[1] = cospi((double)t / 8192.0);
    smv[1] = sinpi((double)t / 8192.0);
#pragma unroll
    for (int m = 2; m < 16; m++) {
        cmv[m] = cmv[m - 1] * cmv[1] - smv[m - 1] * smv[1];
        smv[m] = smv[m - 1] * cmv[1] + cmv[m - 1] * smv[1];
    }

    for (int k = 0; k < 16; k++) {
        int s = k << 8;
        double a0 = (double)h0[s];
        double b0 = (double)h0[s + 4096];
        double c0v = (double)h0[s + 8192];
        double d0 = (double)h0[s + 12288];
        double a1 = (double)h1[s];
        double b1 = (double)h1[s + 4096];
        double c1v = (double)h1[s + 8192];
        double d1 = (double)h1[s + 12288];

        double t10 = a0 + c0v, t20 = b0 + d0;
        double g00 = t10 + t20, g20 = t10 - t20;
        double ar0 = a0 - c0v, br0 = b0 - d0;
        double t11 = a1 + c1v, t21 = b1 + d1;
        double g01 = t11 + t21, g21 = t11 - t21;
        double ar1 = a1 - c1v, br1 = b1 - d1;

        acc[0] += g00;
        acc[32] += g01;
#pragma unroll
        for (int m = 1; m < 16; m++) {
            double c = cmv[m], s_ = smv[m];
            if ((m & 1) == 0) {
                double g0x = (m & 2) ? g20 : g00;
                double g1x = (m & 2) ? g21 : g01;
                acc[m]      = fma(g0x, c,  acc[m]);
                acc[16 + m] = fma(g0x, s_, acc[16 + m]);
                acc[32 + m] = fma(g1x, c,  acc[32 + m]);
                acc[48 + m] = fma(g1x, s_, acc[48 + m]);
            } else if ((m & 2) == 0) {
                acc[m]      = fma(ar0, c,  fma(-br0, s_, acc[m]));
                acc[16 + m] = fma(ar0, s_, fma( br0, c,  acc[16 + m]));
                acc[32 + m] = fma(ar1, c,  fma(-br1, s_, acc[32 + m]));
                acc[48 + m] = fma(ar1, s_, fma( br1, c,  acc[48 + m]));
            } else {
                acc[m]      = fma(ar0, c,  fma( br0, s_, acc[m]));
                acc[16 + m] = fma(ar0, s_, fma(-br0, c,  acc[16 + m]));
                acc[32 + m] = fma(ar1, c,  fma( br1, s_, acc[32 + m]));
                acc[48 + m] = fma(ar1, s_, fma(-br1, c,  acc[48 + m]));
            }
        }
#pragma unroll
        for (int m = 1; m < 16; m++) {
            double cn = cmv[m] * KC_[m] - smv[m] * KS_[m];
            double sn = smv[m] * KC_[m] + cmv[m] * KS_[m];
            cmv[m] = cn; smv[m] = sn;
        }
    }

    int lane = t & 63, wv = t >> 6;
    __shared__ double red[4][64];
#pragma unroll
    for (int k = 0; k < 64; k++) {
        double v = acc[k];
        for (int off = 32; off > 0; off >>= 1) v += __shfl_down(v, off, 64);
        if (lane == 0) red[wv][k] = v;
    }
    __syncthreads();
    if (t < 64) {
        double v = red[0][t] + red[1][t] + red[2][t] + red[3][t];
        int cc = t >> 5, im = (t >> 4) & 1, m = t & 15;
        size_t o = ((size_t)b * HID_ + c0 + cc) * MODES_ + m;
        if (im) Xi[o] = -v;
        else    Xr[o] = v;
    }
}

// ---------------------------------------------------------------------------
// Gate/pack WITH FUSED MX (was a separate kernel): stage X in LDS, compute
// per-head complex mixing into sMr/sMi (256 thr x 4 outputs), then mag/fidx,
// P, means, gating MLP, softmax -> PACKED per-c records:
//   REC[b][c][0..31]  = AB pairs: {k_m*(w1*MX_r+w2*P), m? -k_m*w1*MX_i : 0}
//   REC[b][c][32..39] = w0*sp_W[e][c];  REC[b][c][40] = w0*sp_b[c]; [41]=0
// ---------------------------------------------------------------------------
__global__ __launch_bounds__(256) void k_gate(const double* __restrict__ Xr,
                                              const double* __restrict__ Xi,
                                              const float* __restrict__ mWr,
                                              const float* __restrict__ mWi,
                                              const float* __restrict__ fr_emb_l,
                                              const float* __restrict__ fr_W_l,
                                              const float* __restrict__ fr_b_l,
                                              const double* __restrict__ Eb,
                                              const float* __restrict__ sp_W_l,
                                              const float* __restrict__ sp_b_l,
                                              const float* __restrict__ gW1,
                                              const float* __restrict__ gb1,
                                              const float* __restrict__ gW2,
                                              const float* __restrict__ gb2,
                                              double* __restrict__ RECg) {
    int b = blockIdx.x;
    int t = threadIdx.x;
    __shared__ double sXr[1024], sXi[1024];
    __shared__ double sMr[1024], sMi[1024], sP[1024];
    __shared__ double gg[192], h1s[64], sww[3];
    __shared__ int magI[MODES_];
    __shared__ int fidxS;

    for (int j = t; j < 1024; j += 256) {
        sXr[j] = Xr[(size_t)b * 1024 + j];
        sXi[j] = Xi[(size_t)b * 1024 + j];
    }
    __syncthreads();

    // mag over channels (mean axis=1), truncate
    if (t < MODES_) {
        double acc = 0.0;
        for (int c = 0; c < HID_; c++) {
            double re = sXr[c * MODES_ + t];
            double im = sXi[c * MODES_ + t];
            acc += sqrt(re * re + im * im);
        }
        magI[t] = (int)(acc * (1.0 / 64.0) * 1000.0);
    }

    // MX: of[h,o,m] = sum_i xh[h,i,m] * (Wr + iWi)[h,i,o,m]
    for (int u = t; u < 1024; u += 256) {
        int hh = u >> 8, rem = u & 255, o = rem >> 4, m = rem & 15;
        const float* wr = mWr + (size_t)hh * CH_ * CH_ * MODES_;
        const float* wi = mWi + (size_t)hh * CH_ * CH_ * MODES_;
        double aR = 0.0, aI = 0.0;
#pragma unroll 4
        for (int i = 0; i < CH_; i++) {
            double xrv = sXr[(hh * CH_ + i) * MODES_ + m];
            double xiv = sXi[(hh * CH_ + i) * MODES_ + m];
            double wrv = (double)wr[(i * CH_ + o) * MODES_ + m];
            double wiv = (double)wi[(i * CH_ + o) * MODES_ + m];
            aR += xrv * wrv - xiv * wiv;
            aI += xrv * wiv + xiv * wrv;
        }
        sMr[(hh * CH_ + o) * MODES_ + m] = aR;
        sMi[(hh * CH_ + o) * MODES_ + m] = aI;
    }
    __syncthreads();

    if (t == 0) {
        int ssum = 0;
        for (int m = 0; m < MODES_; m++) ssum += magI[m];
        int f = ssum % NPFR_;
        if (f < 0) f += NPFR_;
        fidxS = f;
    }
    __syncthreads();

    {
        const float* fe = fr_emb_l + fidxS * ED_;
        for (int u = t; u < 1024; u += 256) {
            double acc = 0.0;
            for (int e = 0; e < ED_; e++)
                acc += (double)fe[e] * (double)fr_W_l[e * 1024 + u];
            sP[u] = acc + (double)fr_b_l[u];
        }
    }
    __syncthreads();

    if (t < 64) {
        double a = 0.0;
        for (int e = 0; e < ED_; e++)
            a += Eb[b * ED_ + e] * (double)sp_W_l[e * 64 + t];
        gg[t]       = a * (1.0 / 16384.0) + (double)sp_b_l[t];
        gg[64 + t]  = sMr[t * MODES_] * (1.0 / 16384.0);
        gg[128 + t] = sP[t * MODES_] * (1.0 / 16384.0);
    }
    __syncthreads();
    if (t < 64) {
        double a = 0.0;
        for (int k = 0; k < 192; k++) a += gg[k] * (double)gW1[k * 64 + t];
        a += (double)gb1[t];
        h1s[t] = a > 0.0 ? a : 0.0;
    }
    __syncthreads();
    if (t == 0) {
        double l[3];
        for (int j = 0; j < 3; j++) {
            double a = 0.0;
            for (int k = 0; k < 64; k++) a += h1s[k] * (double)gW2[k * 3 + j];
            l[j] = a + (double)gb2[j];
        }
        double mx = fmax(l[0], fmax(l[1], l[2]));
        double e0 = exp(l[0] - mx), e1 = exp(l[1] - mx), e2 = exp(l[2] - mx);
        double sum = e0 + e1 + e2;
        sww[0] = e0 / sum; sww[1] = e1 / sum; sww[2] = e2 / sum;
    }
    __syncthreads();

    double w0s = sww[0], w1s = sww[1], w2s = sww[2];
    double* R = RECg + (size_t)b * HID_ * RECW_;
    for (int u = t; u < 1024; u += 256) {
        int c = u >> 4, m = u & 15;
        double km = (m == 0 ? 1.0 : 2.0) * (1.0 / 16384.0);
        R[c * RECW_ + 2 * m]     = km * (w1s * sMr[u] + w2s * sP[u]);
        R[c * RECW_ + 2 * m + 1] = (m == 0) ? 0.0 : -(km * w1s * sMi[u]);
    }
    for (int u = t; u < 512; u += 256) {
        int e = u >> 6, c = u & 63;
        R[c * RECW_ + 32 + e] = w0s * (double)sp_W_l[u];
    }
    if (t < 64) {
        R[t * RECW_ + 40] = w0s * (double)sp_b_l[t];
        R[t * RECW_ + 41] = 0.0;
    }
}

// ---------------------------------------------------------------------------
// Reconstruction: PAIRED positions (s, s+8192) per thread, CHANNEL-SPLIT
// across blockIdx.z (32 channels each) for 2x occupancy (grid 32 x B x 2 =
// 1024 blocks, 28.6 KB LDS -> 4 blocks/CU). Even/odd mode partials vE,vO
// computed once serve both outputs: v1 = base1+vE+vO, v2 = base2+vE-vO.
// Partial channel-sums to sC2[z][b][s]; k_hash adds the halves.
// ---------------------------------------------------------------------------
__global__ __launch_bounds__(256) void k_recon(const int* __restrict__ idx,
                                               const float* __restrict__ sp_emb_l,
                                               const double* __restrict__ RECg,
                                               float* __restrict__ h,
                                               double* __restrict__ sC2) {
    int b = blockIdx.y;
    int cz = blockIdx.z;
    int cbase = cz * 32;
    int s1 = blockIdx.x * 256 + threadIdx.x;   // [0, 8192)
    int s2 = s1 + 8192;
    int t = threadIdx.x;
    __shared__ double rec[32 * RECW_];     // 10.5 KB
    __shared__ float semb[NPSP_ * 9];      // 18 KB, stride 9
    for (int j = t; j < 32 * RECW_; j += 256)
        rec[j] = RECg[(size_t)b * HID_ * RECW_ + cbase * RECW_ + j];
    for (int j = t; j < NPSP_ * 8; j += 256) {
        int r = j >> 3, e2i = j & 7;
        semb[r * 9 + e2i] = sp_emb_l[j];
    }
    __syncthreads();

    int id1 = idx[(size_t)b * S_ + s1];
    int id2 = idx[(size_t)b * S_ + s2];
    double e1[8], e2[8];
#pragma unroll
    for (int k = 0; k < 8; k++) e1[k] = (double)semb[id1 * 9 + k];
#pragma unroll
    for (int k = 0; k < 8; k++) e2[k] = (double)semb[id2 * 9 + k];

    double cb = cospi((double)s1 / 8192.0);
    double sb = sinpi((double)s1 / 8192.0);
    double cm[16], sm[16];
    cm[0] = 1.0; sm[0] = 0.0;
    cm[1] = cb;  sm[1] = sb;
#pragma unroll
    for (int m = 2; m < 16; m++) {
        cm[m] = cm[m - 1] * cb - sm[m - 1] * sb;
        sm[m] = sm[m - 1] * cb + cm[m - 1] * sb;
    }

    float* hb = h + (size_t)b * HID_ * S_ + (size_t)cbase * S_;
    double cs1 = 0.0, cs2 = 0.0;
    for (int c = 0; c < 32; c++) {
        const double2* r2 = (const double2*)(rec + c * RECW_);
        double base = rec[c * RECW_ + 40];
        double p1 = base, p2 = base;
#pragma unroll
        for (int k = 0; k < 4; k++) {
            double2 w = r2[16 + k];
            p1 = fma(e1[2 * k], w.x, p1);
            p1 = fma(e1[2 * k + 1], w.y, p1);
            p2 = fma(e2[2 * k], w.x, p2);
            p2 = fma(e2[2 * k + 1], w.y, p2);
        }
        double vE = 0.0, vO = 0.0;
#pragma unroll
        for (int m = 0; m < 16; m += 2) {
            double2 qe = r2[m];
            double2 qo = r2[m + 1];
            vE = fma(qe.x, cm[m], vE);
            vE = fma(qe.y, sm[m], vE);
            vO = fma(qo.x, cm[m + 1], vO);
            vO = fma(qo.y, sm[m + 1], vO);
        }
        double g1 = gelu_exact(p1 + (vE + vO));
        double g2 = gelu_exact(p2 + (vE - vO));
        hb[(size_t)c * S_ + s1] = (float)g1;
        hb[(size_t)c * S_ + s2] = (float)g2;
        cs1 += g1;
        cs2 += g2;
    }
    sC2[(size_t)(cz * B_ + b) * S_ + s1] = cs1;
    sC2[(size_t)(cz * B_ + b) * S_ + s2] = cs2;
}

// ---------------------------------------------------------------------------
// Projection: out[b,s] = sum_d h[b,d,s]*pW[d] + pb
// ---------------------------------------------------------------------------
__global__ __launch_bounds__(256) void k_proj(const float* __restrict__ h,
                                              const float* __restrict__ pW,
                                              const float* __restrict__ pb,
                                              float* __restrict__ out) {
    int b = blockIdx.y;
    int s = blockIdx.x * 256 + threadIdx.x;
    const float* hb = h + (size_t)b * HID_ * S_ + s;
    double acc = 0.0;
    for (int d = 0; d < HID_; d++)
        acc += (double)hb[(size_t)d * S_] * (double)pW[d];
    out[(size_t)b * S_ + s] = (float)(acc + (double)pb[0]);
}

extern "C" void kernel_launch(void* const* d_in, const int* in_sizes, int n_in,
                              void* d_out, int out_size, void* d_ws, size_t ws_size,
                              hipStream_t stream) {
    const float* x      = (const float*)d_in[0];
    const float* lift_W = (const float*)d_in[1];
    const float* lift_b = (const float*)d_in[2];
    const float* proj_W = (const float*)d_in[3];
    const float* proj_b = (const float*)d_in[4];
    const float* sp_emb = (const float*)d_in[5];
    const float* sp_W   = (const float*)d_in[6];
    const float* sp_b   = (const float*)d_in[7];
    const float* fr_emb = (const float*)d_in[8];
    const float* fr_W   = (const float*)d_in[9];
    const float* fr_b   = (const float*)d_in[10];
    const float* g_W1   = (const float*)d_in[11];
    const float* g_b1   = (const float*)d_in[12];
    const float* g_W2   = (const float*)d_in[13];
    const float* g_b2   = (const float*)d_in[14];
    const float* mhf_Wr = (const float*)d_in[15];
    const float* mhf_Wi = (const float*)d_in[16];

    char* ws = (char*)d_ws;
    float* h    = (float*)ws;   ws += (size_t)B_ * HID_ * S_ * 4;   // 64 MiB
    double* sC2 = (double*)ws;  ws += (size_t)2 * B_ * S_ * 8;      // 4 MiB
    int* idx    = (int*)ws;     ws += (size_t)B_ * S_ * 4;          // 1 MiB
    double* Xr  = (double*)ws;  ws += (size_t)B_ * HID_ * MODES_ * 8;
    double* Xi  = (double*)ws;  ws += (size_t)B_ * HID_ * MODES_ * 8;
    double* REC = (double*)ws;  ws += (size_t)B_ * HID_ * RECW_ * 8;
    double* Eb  = (double*)ws;  ws += (size_t)LAYERS_ * B_ * ED_ * 8;

    hipMemsetAsync(Eb, 0, (size_t)LAYERS_ * B_ * ED_ * 8, stream);

    dim3 blk(256);
    k_lift<<<dim3(S_ / 256, B_), blk, 0, stream>>>(x, lift_W, lift_b, h, sC2);

    for (int lay = 0; lay < LAYERS_; ++lay) {
        k_hash<<<dim3(S_ / 256, B_), blk, 0, stream>>>(
            sC2, sp_emb + (size_t)lay * NPSP_ * ED_, idx, Eb + (size_t)lay * B_ * ED_);
        k_dft<<<dim3(HID_ / 2, B_), blk, 0, stream>>>(h, Xr, Xi);
        k_gate<<<dim3(B_), blk, 0, stream>>>(
            Xr, Xi,
            mhf_Wr + (size_t)lay * HEADS_ * CH_ * CH_ * MODES_,
            mhf_Wi + (size_t)lay * HEADS_ * CH_ * CH_ * MODES_,
            fr_emb + (size_t)lay * NPFR_ * ED_,
            fr_W + (size_t)lay * ED_ * HID_ * MODES_,
            fr_b + (size_t)lay * HID_ * MODES_,
            Eb + (size_t)lay * B_ * ED_,
            sp_W + (size_t)lay * ED_ * HID_,
            sp_b + (size_t)lay * HID_,
            g_W1 + (size_t)lay * 192 * 64,
            g_b1 + (size_t)lay * 64,
            g_W2 + (size_t)lay * 64 * 3,
            g_b2 + (size_t)lay * 3,
            REC);
        k_recon<<<dim3(S_ / 512, B_, 2), blk, 0, stream>>>(
            idx, sp_emb + (size_t)lay * NPSP_ * ED_, REC, h, sC2);
    }

    k_proj<<<dim3(S_ / 256, B_), blk, 0, stream>>>(h, proj_W, proj_b, (float*)d_out);
}

// Round 9
// 568.985 us; speedup vs baseline: 1.0468x; 1.0468x over previous
//
#include <hip/hip_runtime.h>
#include <math.h>

#define B_ 16
#define CIN_ 3
#define HID_ 64
#define S_ 16384
#define MODES_ 16
#define HEADS_ 4
#define CH_ 16
#define ED_ 8
#define NPSP_ 500
#define NPFR_ 200
#define LAYERS_ 4
#define RECW_ 42                      // per-channel packed record, doubles

// gelu(v), erf via 12-term odd Taylor in y=v/sqrt(2); |err|<2e-14 for |v|<=1,
// rare libm fallback. h stored f32 (3e-9 rounding) dominates — poly is free.
__device__ __forceinline__ double gelu_exact(double v) {
    double y = v * 0.70710678118654752440;
    double t = y * y;
    double p = -1.2290555301717926e-09;
    p = fma(p, t, 1.4807192815879218e-08);
    p = fma(p, t, -1.6365838718281893e-07);
    p = fma(p, t, 1.6462114365889246e-06);
    p = fma(p, t, -1.4925650358406251e-05);
    p = fma(p, t, 1.2055332981789664e-04);
    p = fma(p, t, -8.5483270234508528e-04);
    p = fma(p, t, 5.2239776254421878e-03);
    p = fma(p, t, -2.6866170645131252e-02);
    p = fma(p, t, 1.1283791670955126e-01);
    p = fma(p, t, -3.7612638903183752e-01);
    p = fma(p, t, 1.1283791670955126e+00);
    double er = y * p;
    if (t > 0.5000001) er = erf(y);
    return 0.5 * v * (1.0 + er);
}

// cos(m*pi/32), sin(m*pi/32), m = 0..15
__device__ __constant__ double KC_[16] = {1.0, 0.99518472667219688624,
    0.98078528040323044913, 0.95694033573220886494, 0.92387953251128675613,
    0.88192126434835502971, 0.83146961230254523708, 0.77301045336273696081,
    0.70710678118654752440, 0.63439328416364549822, 0.55557023301960222474,
    0.47139673682599764856, 0.38268343236508977173, 0.29028467725446236764,
    0.19509032201612826785, 0.09801714032956060199};
__device__ __constant__ double KS_[16] = {0.0, 0.09801714032956060199,
    0.19509032201612826785, 0.29028467725446236764, 0.38268343236508977173,
    0.47139673682599764856, 0.55557023301960222474, 0.63439328416364549822,
    0.70710678118654752440, 0.77301045336273696081, 0.83146961230254523708,
    0.88192126434835502971, 0.92387953251128675613, 0.95694033573220886494,
    0.98078528040323044913, 0.99518472667219688624};

// ---------------------------------------------------------------------------
// Lift: h[b,d,s] = sum_c x[b,c,s]*W[c,d] + bias[d].  Channel-sum written as
// two partials (d<32 / d>=32) matching k_recon's split-channel layout.
// ---------------------------------------------------------------------------
__global__ __launch_bounds__(256) void k_lift(const float* __restrict__ x,
                                              const float* __restrict__ W,
                                              const float* __restrict__ bias,
                                              float* __restrict__ h,
                                              double* __restrict__ sC2) {
    int b = blockIdx.y;
    int s = blockIdx.x * 256 + threadIdx.x;
    const float* xb = x + (size_t)b * CIN_ * S_ + s;
    double x0 = (double)xb[0];
    double x1 = (double)xb[S_];
    double x2 = (double)xb[2 * S_];
    float* hb = h + (size_t)b * HID_ * S_ + s;
    double accA = 0.0, accB = 0.0;
    for (int d = 0; d < HID_; ++d) {
        double v = x0 * (double)W[d];
        v = fma(x1, (double)W[HID_ + d], v);
        v = fma(x2, (double)W[2 * HID_ + d], v);
        v += (double)bias[d];
        hb[(size_t)d * S_] = (float)v;
        if (d < 32) accA += v; else accB += v;
    }
    sC2[(size_t)b * S_ + s] = accA;
    sC2[(size_t)(B_ + b) * S_ + s] = accB;
}

// ---------------------------------------------------------------------------
// Spatial hash: wsum window over (sC2 half0 + half1), idx, block-reduced
// embedding sum (Eb).
// ---------------------------------------------------------------------------
__global__ __launch_bounds__(256) void k_hash(const double* __restrict__ sC2,
                                              const float* __restrict__ emb_l,
                                              int* __restrict__ idx,
                                              double* __restrict__ Eb) {
    int b = blockIdx.y;
    int s0 = blockIdx.x * 256;
    int t = threadIdx.x;
    __shared__ double sl[260];
    for (int j = t; j < 260; j += 256) {
        int p = s0 - 2 + j;
        p = p < 0 ? 0 : (p > S_ - 1 ? S_ - 1 : p);
        sl[j] = sC2[(size_t)b * S_ + p] + sC2[(size_t)(B_ + b) * S_ + p];
    }
    __syncthreads();
    double wsum = ((sl[t] + sl[t + 1]) + sl[t + 2]) + sl[t + 3];
    int ti = (int)(wsum * 31.0);
    int id = ti % NPSP_;
    if (id < 0) id += NPSP_;
    idx[(size_t)b * S_ + s0 + t] = id;

    const float* er = emb_l + id * ED_;
    double ev[8];
#pragma unroll
    for (int k = 0; k < 8; k++) ev[k] = (double)er[k];

    int lane = t & 63, wv = t >> 6;
    __shared__ double red[4][8];
#pragma unroll
    for (int k = 0; k < 8; k++) {
        double v = ev[k];
        for (int off = 32; off > 0; off >>= 1) v += __shfl_down(v, off, 64);
        if (lane == 0) red[wv][k] = v;
    }
    __syncthreads();
    if (t < 8) {
        double v = red[0][t] + red[1][t] + red[2][t] + red[3][t];
        atomicAdd(&Eb[b * ED_ + t], v);
    }
}

// ---------------------------------------------------------------------------
// 16-mode DFT, radix-4 decimation, 2 channels/block — ROUND-5 PROVEN SHAPE.
// __launch_bounds__(256, 2) is LOAD-BEARING (round-6 spill disaster without).
// ---------------------------------------------------------------------------
__global__ __launch_bounds__(256, 2) void k_dft(const float* __restrict__ h,
                                                double* __restrict__ Xr,
                                                double* __restrict__ Xi) {
    int b = blockIdx.y;
    int c0 = blockIdx.x * 2;
    int t = threadIdx.x;
    const float* h0 = h + ((size_t)(b * HID_ + c0)) * S_ + t;
    const float* h1 = h0 + S_;

    double acc[64];
#pragma unroll
    for (int k = 0; k < 64; k++) acc[k] = 0.0;

    double cmv[16], smv[16];
    cmv[0] = 1.0; smv[0] = 0.0;
    cmv[1] = cospi((double)t / 8192.0);
    smv[1] = sinpi((double)t / 8192.0);
#pragma unroll
    for (int m = 2; m < 16; m++) {
        cmv[m] = cmv[m - 1] * cmv[1] - smv[m - 1] * smv[1];
        smv[m] = smv[m - 1] * cmv[1] + cmv[m - 1] * smv[1];
    }

    for (int k = 0; k < 16; k++) {
        int s = k << 8;
        double a0 = (double)h0[s];
        double b0 = (double)h0[s + 4096];
        double c0v = (double)h0[s + 8192];
        double d0 = (double)h0[s + 12288];
        double a1 = (double)h1[s];
        double b1 = (double)h1[s + 4096];
        double c1v = (double)h1[s + 8192];
        double d1 = (double)h1[s + 12288];

        double t10 = a0 + c0v, t20 = b0 + d0;
        double g00 = t10 + t20, g20 = t10 - t20;
        double ar0 = a0 - c0v, br0 = b0 - d0;
        double t11 = a1 + c1v, t21 = b1 + d1;
        double g01 = t11 + t21, g21 = t11 - t21;
        double ar1 = a1 - c1v, br1 = b1 - d1;

        acc[0] += g00;
        acc[32] += g01;
#pragma unroll
        for (int m = 1; m < 16; m++) {
            double c = cmv[m], s_ = smv[m];
            if ((m & 1) == 0) {
                double g0x = (m & 2) ? g20 : g00;
                double g1x = (m & 2) ? g21 : g01;
                acc[m]      = fma(g0x, c,  acc[m]);
                acc[16 + m] = fma(g0x, s_, acc[16 + m]);
                acc[32 + m] = fma(g1x, c,  acc[32 + m]);
                acc[48 + m] = fma(g1x, s_, acc[48 + m]);
            } else if ((m & 2) == 0) {
                acc[m]      = fma(ar0, c,  fma(-br0, s_, acc[m]));
                acc[16 + m] = fma(ar0, s_, fma( br0, c,  acc[16 + m]));
                acc[32 + m] = fma(ar1, c,  fma(-br1, s_, acc[32 + m]));
                acc[48 + m] = fma(ar1, s_, fma( br1, c,  acc[48 + m]));
            } else {
                acc[m]      = fma(ar0, c,  fma( br0, s_, acc[m]));
                acc[16 + m] = fma(ar0, s_, fma(-br0, c,  acc[16 + m]));
                acc[32 + m] = fma(ar1, c,  fma( br1, s_, acc[32 + m]));
                acc[48 + m] = fma(ar1, s_, fma(-br1, c,  acc[48 + m]));
            }
        }
#pragma unroll
        for (int m = 1; m < 16; m++) {
            double cn = cmv[m] * KC_[m] - smv[m] * KS_[m];
            double sn = smv[m] * KC_[m] + cmv[m] * KS_[m];
            cmv[m] = cn; smv[m] = sn;
        }
    }

    int lane = t & 63, wv = t >> 6;
    __shared__ double red[4][64];
#pragma unroll
    for (int k = 0; k < 64; k++) {
        double v = acc[k];
        for (int off = 32; off > 0; off >>= 1) v += __shfl_down(v, off, 64);
        if (lane == 0) red[wv][k] = v;
    }
    __syncthreads();
    if (t < 64) {
        double v = red[0][t] + red[1][t] + red[2][t] + red[3][t];
        int cc = t >> 5, im = (t >> 4) & 1, m = t & 15;
        size_t o = ((size_t)b * HID_ + c0 + cc) * MODES_ + m;
        if (im) Xi[o] = -v;
        else    Xr[o] = v;
    }
}

// ---------------------------------------------------------------------------
// Gate/pack with fused MX: stage X in LDS, per-head complex mixing, mag/fidx,
// P, means, gating MLP, softmax -> PACKED per-c records:
//   REC[b][c][0..31]  = AB pairs: {k_m*(w1*MX_r+w2*P), m? -k_m*w1*MX_i : 0}
//   REC[b][c][32..39] = w0*sp_W[e][c];  REC[b][c][40] = w0*sp_b[c]; [41]=0
// ---------------------------------------------------------------------------
__global__ __launch_bounds__(256) void k_gate(const double* __restrict__ Xr,
                                              const double* __restrict__ Xi,
                                              const float* __restrict__ mWr,
                                              const float* __restrict__ mWi,
                                              const float* __restrict__ fr_emb_l,
                                              const float* __restrict__ fr_W_l,
                                              const float* __restrict__ fr_b_l,
                                              const double* __restrict__ Eb,
                                              const float* __restrict__ sp_W_l,
                                              const float* __restrict__ sp_b_l,
                                              const float* __restrict__ gW1,
                                              const float* __restrict__ gb1,
                                              const float* __restrict__ gW2,
                                              const float* __restrict__ gb2,
                                              double* __restrict__ RECg) {
    int b = blockIdx.x;
    int t = threadIdx.x;
    __shared__ double sXr[1024], sXi[1024];
    __shared__ double sMr[1024], sMi[1024], sP[1024];
    __shared__ double gg[192], h1s[64], sww[3];
    __shared__ int magI[MODES_];
    __shared__ int fidxS;

    for (int j = t; j < 1024; j += 256) {
        sXr[j] = Xr[(size_t)b * 1024 + j];
        sXi[j] = Xi[(size_t)b * 1024 + j];
    }
    __syncthreads();

    if (t < MODES_) {
        double acc = 0.0;
        for (int c = 0; c < HID_; c++) {
            double re = sXr[c * MODES_ + t];
            double im = sXi[c * MODES_ + t];
            acc += sqrt(re * re + im * im);
        }
        magI[t] = (int)(acc * (1.0 / 64.0) * 1000.0);
    }

    for (int u = t; u < 1024; u += 256) {
        int hh = u >> 8, rem = u & 255, o = rem >> 4, m = rem & 15;
        const float* wr = mWr + (size_t)hh * CH_ * CH_ * MODES_;
        const float* wi = mWi + (size_t)hh * CH_ * CH_ * MODES_;
        double aR = 0.0, aI = 0.0;
#pragma unroll 4
        for (int i = 0; i < CH_; i++) {
            double xrv = sXr[(hh * CH_ + i) * MODES_ + m];
            double xiv = sXi[(hh * CH_ + i) * MODES_ + m];
            double wrv = (double)wr[(i * CH_ + o) * MODES_ + m];
            double wiv = (double)wi[(i * CH_ + o) * MODES_ + m];
            aR += xrv * wrv - xiv * wiv;
            aI += xrv * wiv + xiv * wrv;
        }
        sMr[(hh * CH_ + o) * MODES_ + m] = aR;
        sMi[(hh * CH_ + o) * MODES_ + m] = aI;
    }
    __syncthreads();

    if (t == 0) {
        int ssum = 0;
        for (int m = 0; m < MODES_; m++) ssum += magI[m];
        int f = ssum % NPFR_;
        if (f < 0) f += NPFR_;
        fidxS = f;
    }
    __syncthreads();

    {
        const float* fe = fr_emb_l + fidxS * ED_;
        for (int u = t; u < 1024; u += 256) {
            double acc = 0.0;
            for (int e = 0; e < ED_; e++)
                acc += (double)fe[e] * (double)fr_W_l[e * 1024 + u];
            sP[u] = acc + (double)fr_b_l[u];
        }
    }
    __syncthreads();

    if (t < 64) {
        double a = 0.0;
        for (int e = 0; e < ED_; e++)
            a += Eb[b * ED_ + e] * (double)sp_W_l[e * 64 + t];
        gg[t]       = a * (1.0 / 16384.0) + (double)sp_b_l[t];
        gg[64 + t]  = sMr[t * MODES_] * (1.0 / 16384.0);
        gg[128 + t] = sP[t * MODES_] * (1.0 / 16384.0);
    }
    __syncthreads();
    if (t < 64) {
        double a = 0.0;
        for (int k = 0; k < 192; k++) a += gg[k] * (double)gW1[k * 64 + t];
        a += (double)gb1[t];
        h1s[t] = a > 0.0 ? a : 0.0;
    }
    __syncthreads();
    if (t == 0) {
        double l[3];
        for (int j = 0; j < 3; j++) {
            double a = 0.0;
            for (int k = 0; k < 64; k++) a += h1s[k] * (double)gW2[k * 3 + j];
            l[j] = a + (double)gb2[j];
        }
        double mx = fmax(l[0], fmax(l[1], l[2]));
        double e0 = exp(l[0] - mx), e1 = exp(l[1] - mx), e2 = exp(l[2] - mx);
        double sum = e0 + e1 + e2;
        sww[0] = e0 / sum; sww[1] = e1 / sum; sww[2] = e2 / sum;
    }
    __syncthreads();

    double w0s = sww[0], w1s = sww[1], w2s = sww[2];
    double* R = RECg + (size_t)b * HID_ * RECW_;
    for (int u = t; u < 1024; u += 256) {
        int c = u >> 4, m = u & 15;
        double km = (m == 0 ? 1.0 : 2.0) * (1.0 / 16384.0);
        R[c * RECW_ + 2 * m]     = km * (w1s * sMr[u] + w2s * sP[u]);
        R[c * RECW_ + 2 * m + 1] = (m == 0) ? 0.0 : -(km * w1s * sMi[u]);
    }
    for (int u = t; u < 512; u += 256) {
        int e = u >> 6, c = u & 63;
        R[c * RECW_ + 32 + e] = w0s * (double)sp_W_l[u];
    }
    if (t < 64) {
        R[t * RECW_ + 40] = w0s * (double)sp_b_l[t];
        R[t * RECW_ + 41] = 0.0;
    }
}

// ---------------------------------------------------------------------------
// Reconstruction: QUARTET positions (s, s+4096, s+8192, s+12288) per thread.
// Basis at s+j*4096 = s-basis rotated by j*m*pi/2 (pure sign/swap). Mode sum
// split into 6 partials by m mod 4 (P=in-phase, Q=quadrature), computed ONCE:
//   v0 = p0 + (u0+w0);  v1 = p1 + (u1+qd);  v2 = p2 + (u0-w0);
//   v3 = p3 + (u1-qd);  u0=PA+PC, u1=PA-PC, w0=PB+PD, qd=QB-QD.
// The 21 LDS broadcasts per c now serve FOUR outputs (was two) — k_recon is
// LDS-stream-bound (R8: doubling blocks changed nothing; VALUBusy 38%).
// Channel-split z (32 c/block). ~185 VGPR under explicit (256,2) — safe.
// ---------------------------------------------------------------------------
__global__ __launch_bounds__(256, 2) void k_recon(const int* __restrict__ idx,
                                                  const float* __restrict__ sp_emb_l,
                                                  const double* __restrict__ RECg,
                                                  float* __restrict__ h,
                                                  double* __restrict__ sC2) {
    int b = blockIdx.y;
    int cz = blockIdx.z;
    int cbase = cz * 32;
    int s0 = blockIdx.x * 256 + threadIdx.x;   // [0, 4096)
    int t = threadIdx.x;
    __shared__ double rec[32 * RECW_];     // 10.5 KB
    __shared__ float semb[NPSP_ * 9];      // 18 KB, stride 9
    for (int j = t; j < 32 * RECW_; j += 256)
        rec[j] = RECg[(size_t)b * HID_ * RECW_ + cbase * RECW_ + j];
    for (int j4 = t; j4 < NPSP_ * 2; j4 += 256) {     // float4 staging
        float4 v = reinterpret_cast<const float4*>(sp_emb_l)[j4];
        int r = j4 >> 1, e0 = (j4 & 1) * 4;
        semb[r * 9 + e0]     = v.x;
        semb[r * 9 + e0 + 1] = v.y;
        semb[r * 9 + e0 + 2] = v.z;
        semb[r * 9 + e0 + 3] = v.w;
    }
    __syncthreads();

    int id0 = idx[(size_t)b * S_ + s0];
    int id1 = idx[(size_t)b * S_ + s0 + 4096];
    int id2 = idx[(size_t)b * S_ + s0 + 8192];
    int id3 = idx[(size_t)b * S_ + s0 + 12288];
    double e0v[8], e1v[8], e2v[8], e3v[8];
#pragma unroll
    for (int k = 0; k < 8; k++) {
        e0v[k] = (double)semb[id0 * 9 + k];
        e1v[k] = (double)semb[id1 * 9 + k];
        e2v[k] = (double)semb[id2 * 9 + k];
        e3v[k] = (double)semb[id3 * 9 + k];
    }

    double cb = cospi((double)s0 / 8192.0);
    double sb = sinpi((double)s0 / 8192.0);
    double cm[16], sm[16];
    cm[0] = 1.0; sm[0] = 0.0;
    cm[1] = cb;  sm[1] = sb;
#pragma unroll
    for (int m = 2; m < 16; m++) {
        cm[m] = cm[m - 1] * cb - sm[m - 1] * sb;
        sm[m] = sm[m - 1] * cb + cm[m - 1] * sb;
    }

    float* hb = h + (size_t)b * HID_ * S_ + (size_t)cbase * S_;
    double cs0 = 0.0, cs1 = 0.0, cs2 = 0.0, cs3 = 0.0;
    for (int c = 0; c < 32; c++) {
        const double2* r2 = (const double2*)(rec + c * RECW_);
        double base = rec[c * RECW_ + 40];
        double p0 = base, p1 = base, p2 = base, p3 = base;
#pragma unroll
        for (int k = 0; k < 4; k++) {
            double2 w = r2[16 + k];
            p0 = fma(e0v[2 * k], w.x, p0); p0 = fma(e0v[2 * k + 1], w.y, p0);
            p1 = fma(e1v[2 * k], w.x, p1); p1 = fma(e1v[2 * k + 1], w.y, p1);
            p2 = fma(e2v[2 * k], w.x, p2); p2 = fma(e2v[2 * k + 1], w.y, p2);
            p3 = fma(e3v[2 * k], w.x, p3); p3 = fma(e3v[2 * k + 1], w.y, p3);
        }
        double PA = 0.0, PB = 0.0, PC = 0.0, PD = 0.0, QB = 0.0, QD = 0.0;
#pragma unroll
        for (int mm = 0; mm < 16; mm += 4) {
            double2 q0 = r2[mm], q1 = r2[mm + 1], q2 = r2[mm + 2], q3 = r2[mm + 3];
            PA = fma(q0.x, cm[mm], PA);     PA = fma(q0.y, sm[mm], PA);
            PB = fma(q1.x, cm[mm + 1], PB); PB = fma(q1.y, sm[mm + 1], PB);
            QB = fma(q1.y, cm[mm + 1], QB); QB = fma(-q1.x, sm[mm + 1], QB);
            PC = fma(q2.x, cm[mm + 2], PC); PC = fma(q2.y, sm[mm + 2], PC);
            PD = fma(q3.x, cm[mm + 3], PD); PD = fma(q3.y, sm[mm + 3], PD);
            QD = fma(q3.y, cm[mm + 3], QD); QD = fma(-q3.x, sm[mm + 3], QD);
        }
        double u0 = PA + PC, u1 = PA - PC;
        double w0 = PB + PD, qd = QB - QD;
        double g0 = gelu_exact(p0 + (u0 + w0));
        double g1 = gelu_exact(p1 + (u1 + qd));
        double g2 = gelu_exact(p2 + (u0 - w0));
        double g3 = gelu_exact(p3 + (u1 - qd));
        hb[(size_t)c * S_ + s0]         = (float)g0;
        hb[(size_t)c * S_ + s0 + 4096]  = (float)g1;
        hb[(size_t)c * S_ + s0 + 8192]  = (float)g2;
        hb[(size_t)c * S_ + s0 + 12288] = (float)g3;
        cs0 += g0; cs1 += g1; cs2 += g2; cs3 += g3;
    }
    double* sc = sC2 + (size_t)(cz * B_ + b) * S_;
    sc[s0]         = cs0;
    sc[s0 + 4096]  = cs1;
    sc[s0 + 8192]  = cs2;
    sc[s0 + 12288] = cs3;
}

// ---------------------------------------------------------------------------
// Projection: out[b,s] = sum_d h[b,d,s]*pW[d] + pb
// ---------------------------------------------------------------------------
__global__ __launch_bounds__(256) void k_proj(const float* __restrict__ h,
                                              const float* __restrict__ pW,
                                              const float* __restrict__ pb,
                                              float* __restrict__ out) {
    int b = blockIdx.y;
    int s = blockIdx.x * 256 + threadIdx.x;
    const float* hb = h + (size_t)b * HID_ * S_ + s;
    double acc = 0.0;
    for (int d = 0; d < HID_; d++)
        acc += (double)hb[(size_t)d * S_] * (double)pW[d];
    out[(size_t)b * S_ + s] = (float)(acc + (double)pb[0]);
}

extern "C" void kernel_launch(void* const* d_in, const int* in_sizes, int n_in,
                              void* d_out, int out_size, void* d_ws, size_t ws_size,
                              hipStream_t stream) {
    const float* x      = (const float*)d_in[0];
    const float* lift_W = (const float*)d_in[1];
    const float* lift_b = (const float*)d_in[2];
    const float* proj_W = (const float*)d_in[3];
    const float* proj_b = (const float*)d_in[4];
    const float* sp_emb = (const float*)d_in[5];
    const float* sp_W   = (const float*)d_in[6];
    const float* sp_b   = (const float*)d_in[7];
    const float* fr_emb = (const float*)d_in[8];
    const float* fr_W   = (const float*)d_in[9];
    const float* fr_b   = (const float*)d_in[10];
    const float* g_W1   = (const float*)d_in[11];
    const float* g_b1   = (const float*)d_in[12];
    const float* g_W2   = (const float*)d_in[13];
    const float* g_b2   = (const float*)d_in[14];
    const float* mhf_Wr = (const float*)d_in[15];
    const float* mhf_Wi = (const float*)d_in[16];

    char* ws = (char*)d_ws;
    float* h    = (float*)ws;   ws += (size_t)B_ * HID_ * S_ * 4;   // 64 MiB
    double* sC2 = (double*)ws;  ws += (size_t)2 * B_ * S_ * 8;      // 4 MiB
    int* idx    = (int*)ws;     ws += (size_t)B_ * S_ * 4;          // 1 MiB
    double* Xr  = (double*)ws;  ws += (size_t)B_ * HID_ * MODES_ * 8;
    double* Xi  = (double*)ws;  ws += (size_t)B_ * HID_ * MODES_ * 8;
    double* REC = (double*)ws;  ws += (size_t)B_ * HID_ * RECW_ * 8;
    double* Eb  = (double*)ws;  ws += (size_t)LAYERS_ * B_ * ED_ * 8;

    hipMemsetAsync(Eb, 0, (size_t)LAYERS_ * B_ * ED_ * 8, stream);

    dim3 blk(256);
    k_lift<<<dim3(S_ / 256, B_), blk, 0, stream>>>(x, lift_W, lift_b, h, sC2);

    for (int lay = 0; lay < LAYERS_; ++lay) {
        k_hash<<<dim3(S_ / 256, B_), blk, 0, stream>>>(
            sC2, sp_emb + (size_t)lay * NPSP_ * ED_, idx, Eb + (size_t)lay * B_ * ED_);
        k_dft<<<dim3(HID_ / 2, B_), blk, 0, stream>>>(h, Xr, Xi);
        k_gate<<<dim3(B_), blk, 0, stream>>>(
            Xr, Xi,
            mhf_Wr + (size_t)lay * HEADS_ * CH_ * CH_ * MODES_,
            mhf_Wi + (size_t)lay * HEADS_ * CH_ * CH_ * MODES_,
            fr_emb + (size_t)lay * NPFR_ * ED_,
            fr_W + (size_t)lay * ED_ * HID_ * MODES_,
            fr_b + (size_t)lay * HID_ * MODES_,
            Eb + (size_t)lay * B_ * ED_,
            sp_W + (size_t)lay * ED_ * HID_,
            sp_b + (size_t)lay * HID_,
            g_W1 + (size_t)lay * 192 * 64,
            g_b1 + (size_t)lay * 64,
            g_W2 + (size_t)lay * 64 * 3,
            g_b2 + (size_t)lay * 3,
            REC);
        k_recon<<<dim3(S_ / 1024, B_, 2), blk, 0, stream>>>(
            idx, sp_emb + (size_t)lay * NPSP_ * ED_, REC, h, sC2);
    }

    k_proj<<<dim3(S_ / 256, B_), blk, 0, stream>>>(h, proj_W, proj_b, (float*)d_out);
}